// Round 4
// baseline (547.532 us; speedup 1.0000x reference)
//
#include <hip/hip_runtime.h>
#include <math.h>

#define SQ   2048
#define DH   64
#define NH   16
#define NB   4
#define QB   64      // q rows per block (4 waves x 16)
#define TK   64      // k rows per tile
#define PST  68      // float row stride for Ps

typedef float f32x4  __attribute__((ext_vector_type(4)));
typedef short s16x8  __attribute__((ext_vector_type(8)));
typedef short s16x4  __attribute__((ext_vector_type(4)));

__device__ __forceinline__ short f2bf(float f) {
    union { float f; unsigned u; } x; x.f = f;
    unsigned r = (x.u + 0x7FFFu + ((x.u >> 16) & 1u)) >> 16;  // RNE
    return (short)(unsigned short)r;
}

__device__ __forceinline__ void gll16(const void* g, void* l) {
    __builtin_amdgcn_global_load_lds(
        (const __attribute__((address_space(1))) unsigned int*)g,
        (__attribute__((address_space(3))) unsigned int*)l, 16, 0, 0);
}

// -------- prepack 1: mask -> transposed bitmask  mb[b][word][row] ----------
// word w (0..63) of row s of batch b lives at mb[(b*64 + w)*SQ + s]
__global__ __launch_bounds__(64)
void mask_pack(const unsigned int* __restrict__ Mg, unsigned int* __restrict__ mb)
{
    const int gr   = blockIdx.x;           // 0 .. NB*SQ-1
    const int b    = gr >> 11;
    const int s    = gr & (SQ - 1);
    const int lane = threadIdx.x;
    bool byteLayout = false;
    #pragma unroll
    for (int i = 0; i < 16; ++i) byteLayout = byteLayout || (Mg[i] > 1u);
    unsigned int* out = mb + (size_t)b * 64 * SQ + s;
    if (!byteLayout) {
        const unsigned int* rp = Mg + (size_t)gr * SQ;
        #pragma unroll 4
        for (int i = 0; i < 32; ++i) {
            unsigned long long bits = __ballot(rp[i * 64 + lane] != 0u);
            if (lane == 0) {
                out[(size_t)(2*i)   * SQ] = (unsigned)bits;
                out[(size_t)(2*i+1) * SQ] = (unsigned)(bits >> 32);
            }
        }
    } else {
        const unsigned char* rp = (const unsigned char*)Mg + (size_t)gr * SQ;
        #pragma unroll 4
        for (int i = 0; i < 32; ++i) {
            unsigned long long bits = __ballot(rp[i * 64 + lane] != 0);
            if (lane == 0) {
                out[(size_t)(2*i)   * SQ] = (unsigned)bits;
                out[(size_t)(2*i+1) * SQ] = (unsigned)(bits >> 32);
            }
        }
    }
}

// ------- prepack 2: K,V f32 -> bf16, tiled 64x64, XOR-swizzled granules ------
__global__ __launch_bounds__(256)
void kv_pack(const float* __restrict__ Kg, const float* __restrict__ Vg,
             short* __restrict__ Ktg, short* __restrict__ Vtg)
{
    __shared__ float Vf[64][68];
    const int tid = threadIdx.x;
    const int bh  = blockIdx.x >> 5;
    const int kt  = blockIdx.x & 31;
    const float* ksrc = Kg + ((size_t)bh * SQ + kt * TK) * DH;
    const float* vsrc = Vg + ((size_t)bh * SQ + kt * TK) * DH;
    short* kd = Ktg + (size_t)(bh * 32 + kt) * 4096;
    short* vd = Vtg + (size_t)(bh * 32 + kt) * 4096;

    #pragma unroll
    for (int ii = 0; ii < 4; ++ii) {
        int idx = tid + ii * 256;          // 0..1023 float4 slots
        int r = idx >> 4, c0 = (idx & 15) * 4;
        float4 kv = *(const float4*)(ksrc + r * DH + c0);
        s16x4 s; s[0]=f2bf(kv.x); s[1]=f2bf(kv.y); s[2]=f2bf(kv.z); s[3]=f2bf(kv.w);
        int gp = (c0 >> 3) ^ (r & 7);
        *(s16x4*)(kd + r * 64 + gp * 8 + (c0 & 7)) = s;
        float4 vv = *(const float4*)(vsrc + r * DH + c0);
        *(float4*)&Vf[r][c0] = vv;
    }
    __syncthreads();
    #pragma unroll
    for (int ii = 0; ii < 4; ++ii) {
        int idx = tid + ii * 256;
        int d = idx >> 4, k0 = (idx & 15) * 4;
        s16x4 s;
        s[0]=f2bf(Vf[k0+0][d]); s[1]=f2bf(Vf[k0+1][d]);
        s[2]=f2bf(Vf[k0+2][d]); s[3]=f2bf(Vf[k0+3][d]);
        int gp = (k0 >> 3) ^ (d & 7);
        *(s16x4*)(vd + d * 64 + gp * 8 + (k0 & 7)) = s;
    }
}

// ------------------------------- hot kernel ---------------------------------
__global__ __launch_bounds__(256)
void attn_fused(const float* __restrict__ Qg,
                const short* __restrict__ Ktg, const short* __restrict__ Vtg,
                const unsigned int* __restrict__ mb,
                float* __restrict__ Og, float* __restrict__ Pg)
{
    __shared__ __align__(16) short Ks[2][4096];    // 16 KB (dbuf swizzled K tile)
    __shared__ __align__(16) short Vt[2][4096];    // 16 KB (dbuf swizzled V^T tile)
    __shared__ __align__(16) float Ps[4][16][PST]; // 17 KB (per-wave P tile)

    const int tid  = threadIdx.x;
    const int lane = tid & 63;
    const int wv   = tid >> 6;
    const int lq   = lane & 15;
    const int lk   = lane >> 4;

    const int bh = blockIdx.y;
    const int b  = bh >> 4;
    const int q0 = blockIdx.x * QB;

    // ---- Q A-fragments from f32 (row = lq, k = 32c + 8*lk + j) ----
    s16x8 qf[2];
    {
        const float* qrow = Qg + ((size_t)bh * SQ + q0 + wv * 16 + lq) * DH;
        #pragma unroll
        for (int c = 0; c < 2; ++c) {
            const float4* p = (const float4*)(qrow + c * 32 + lk * 8);
            float4 a = p[0], bb = p[1];
            qf[c][0]=f2bf(a.x);  qf[c][1]=f2bf(a.y);  qf[c][2]=f2bf(a.z);  qf[c][3]=f2bf(a.w);
            qf[c][4]=f2bf(bb.x); qf[c][5]=f2bf(bb.y); qf[c][6]=f2bf(bb.z); qf[c][7]=f2bf(bb.w);
        }
    }

    const size_t ktb  = (size_t)bh * 32;
    const int    stgo = wv * 512 + lane * 8;           // staging offset (shorts)
    const int swz0 = (lk ^ (lq & 7)) << 3;
    const int swz1 = ((4 + lk) ^ (lq & 7)) << 3;
    // per-kt mask gather: lanes 0..15 -> half 0 rows 0..15, 16..31 -> half 1, dup above
    const size_t mbase = (size_t)b * 64 * SQ + q0 + wv * 16 + ((size_t)((lane >> 4) & 1)) * SQ + (lane & 15);

    // ================= sweep 1: row max m, denom l =================
    float m[4], l[4];
    #pragma unroll
    for (int r = 0; r < 4; ++r) { m[r] = -3.3e38f; l[r] = 0.f; }

    {   // prologue: stage K tile 0
        const short* ks = Ktg + ktb * 4096 + stgo;
        gll16(ks,        &Ks[0][stgo]);
        gll16(ks + 2048, &Ks[0][2048 + stgo]);
    }
    __syncthreads();

    #pragma unroll 1
    for (int kt = 0; kt < SQ / TK; ++kt) {
        const int cb = kt & 1;
        if (kt + 1 < SQ / TK) {   // prefetch next K tile into other buffer
            const short* ks = Ktg + (ktb + kt + 1) * 4096 + stgo;
            gll16(ks,        &Ks[cb ^ 1][stgo]);
            gll16(ks + 2048, &Ks[cb ^ 1][2048 + stgo]);
        }
        const unsigned mw = mb[mbase + (size_t)(kt * 2) * SQ];

        f32x4 acc[4];
        #pragma unroll
        for (int nt = 0; nt < 4; ++nt) {
            acc[nt] = (f32x4){0.f, 0.f, 0.f, 0.f};
            const int R = nt * 16 + lq;
            s16x8 kf0 = *(const s16x8*)(&Ks[cb][R * 64] + swz0);
            s16x8 kf1 = *(const s16x8*)(&Ks[cb][R * 64] + swz1);
            acc[nt] = __builtin_amdgcn_mfma_f32_16x16x32_bf16(qf[0], kf0, acc[nt], 0, 0, 0);
            acc[nt] = __builtin_amdgcn_mfma_f32_16x16x32_bf16(qf[1], kf1, acc[nt], 0, 0, 0);
        }
        #pragma unroll
        for (int r = 0; r < 4; ++r) {
            const unsigned bits0 = __shfl(mw, lk * 4 + r, 64);
            const unsigned bits1 = __shfl(mw, 16 + lk * 4 + r, 64);
            float w[4];
            #pragma unroll
            for (int nt = 0; nt < 4; ++nt) {
                float x = acc[nt][r] * 0.125f;
                unsigned bits = (nt < 2) ? bits0 : bits1;
                if ((bits >> ((nt * 16 + lq) & 31)) & 1u) x = -1e30f;
                w[nt] = x;
            }
            float tmax = fmaxf(fmaxf(w[0], w[1]), fmaxf(w[2], w[3]));
            float lt = __expf(w[0]-tmax) + __expf(w[1]-tmax) + __expf(w[2]-tmax) + __expf(w[3]-tmax);
            float mn = fmaxf(m[r], tmax);
            l[r] = l[r] * __expf(m[r] - mn) + lt * __expf(tmax - mn);
            m[r] = mn;
        }
        __syncthreads();   // waits prefetch (vmcnt drain) + protects buffer swap
    }

    // ---- reduce (m,l) across the 16 column-lanes of each row group ----
    float linv[4];
    #pragma unroll
    for (int r = 0; r < 4; ++r) {
        #pragma unroll
        for (int x = 1; x < 16; x <<= 1) {
            float mo = __shfl_xor(m[r], x, 64);
            float lo = __shfl_xor(l[r], x, 64);
            float mn = fmaxf(m[r], mo);
            l[r] = l[r] * __expf(m[r] - mn) + lo * __expf(mo - mn);
            m[r] = mn;
        }
        linv[r] = 1.0f / l[r];
    }

    // ================= sweep 2: P write + O = P.V =================
    f32x4 oa[4];
    #pragma unroll
    for (int dt = 0; dt < 4; ++dt) oa[dt] = (f32x4){0.f, 0.f, 0.f, 0.f};

    {   // prologue: stage K+V tile 0
        const short* ks = Ktg + ktb * 4096 + stgo;
        const short* vs = Vtg + ktb * 4096 + stgo;
        gll16(ks,        &Ks[0][stgo]);
        gll16(ks + 2048, &Ks[0][2048 + stgo]);
        gll16(vs,        &Vt[0][stgo]);
        gll16(vs + 2048, &Vt[0][2048 + stgo]);
    }
    __syncthreads();

    #pragma unroll 1
    for (int kt = 0; kt < SQ / TK; ++kt) {
        const int cb = kt & 1;
        if (kt + 1 < SQ / TK) {   // prefetch next K+V tiles
            const short* ks = Ktg + (ktb + kt + 1) * 4096 + stgo;
            const short* vs = Vtg + (ktb + kt + 1) * 4096 + stgo;
            gll16(ks,        &Ks[cb ^ 1][stgo]);
            gll16(ks + 2048, &Ks[cb ^ 1][2048 + stgo]);
            gll16(vs,        &Vt[cb ^ 1][stgo]);
            gll16(vs + 2048, &Vt[cb ^ 1][2048 + stgo]);
        }
        const unsigned mw = mb[mbase + (size_t)(kt * 2) * SQ];
        unsigned b0[4], b1[4];
        #pragma unroll
        for (int r = 0; r < 4; ++r) {
            b0[r] = __shfl(mw, lk * 4 + r, 64);
            b1[r] = __shfl(mw, 16 + lk * 4 + r, 64);
        }

        #pragma unroll
        for (int nt = 0; nt < 4; ++nt) {
            f32x4 acc = {0.f, 0.f, 0.f, 0.f};
            const int R = nt * 16 + lq;
            s16x8 kf0 = *(const s16x8*)(&Ks[cb][R * 64] + swz0);
            s16x8 kf1 = *(const s16x8*)(&Ks[cb][R * 64] + swz1);
            acc = __builtin_amdgcn_mfma_f32_16x16x32_bf16(qf[0], kf0, acc, 0, 0, 0);
            acc = __builtin_amdgcn_mfma_f32_16x16x32_bf16(qf[1], kf1, acc, 0, 0, 0);
            #pragma unroll
            for (int r = 0; r < 4; ++r) {
                float x = acc[r] * 0.125f;
                unsigned bits = (nt < 2) ? b0[r] : b1[r];
                if ((bits >> ((nt * 16 + lq) & 31)) & 1u) x = -1e30f;
                float p = __expf(x - m[r]) * linv[r];
                Ps[wv][lk * 4 + r][nt * 16 + lq] = p;
            }
        }
        // Ps is per-wave: wave-local LDS visibility is enough (rule #18 pattern)
        asm volatile("s_waitcnt lgkmcnt(0)" ::: "memory");
        __builtin_amdgcn_sched_barrier(0);

        // coalesced P write: 256B bursts
        float* Pw = Pg + (size_t)bh * SQ * SQ + (size_t)(q0 + wv * 16) * SQ + kt * TK;
        #pragma unroll
        for (int i = 0; i < 4; ++i) {
            int f = lane + i * 64;
            int row = f >> 4, c4 = f & 15;
            float4 pv = *(const float4*)&Ps[wv][row][c4 * 4];
            *(float4*)(Pw + (size_t)row * SQ + c4 * 4) = pv;
        }

        // PV MFMAs
        #pragma unroll
        for (int c = 0; c < 2; ++c) {
            const float4* pp = (const float4*)&Ps[wv][lq][c * 32 + lk * 8];
            float4 a0 = pp[0], a1 = pp[1];
            s16x8 pa;
            pa[0]=f2bf(a0.x); pa[1]=f2bf(a0.y); pa[2]=f2bf(a0.z); pa[3]=f2bf(a0.w);
            pa[4]=f2bf(a1.x); pa[5]=f2bf(a1.y); pa[6]=f2bf(a1.z); pa[7]=f2bf(a1.w);
            #pragma unroll
            for (int dt = 0; dt < 4; ++dt) {
                const int Rv = dt * 16 + lq;
                const int swzv = (((4 * c + lk) ^ (lq & 7)) << 3);
                s16x8 vb = *(const s16x8*)(&Vt[cb][Rv * 64] + swzv);
                oa[dt] = __builtin_amdgcn_mfma_f32_16x16x32_bf16(pa, vb, oa[dt], 0, 0, 0);
            }
        }
        __syncthreads();   // waits prefetch + protects buffer swap + Ps WAR
    }

    // ---- write O ----
    {
        float* orow = Og + ((size_t)bh * SQ + q0 + wv * 16) * DH;
        #pragma unroll
        for (int dt = 0; dt < 4; ++dt)
            #pragma unroll
            for (int r = 0; r < 4; ++r)
                orow[(size_t)(lk * 4 + r) * DH + dt * 16 + lq] = oa[dt][r];
    }
}

extern "C" void kernel_launch(void* const* d_in, const int* in_sizes, int n_in,
                              void* d_out, int out_size, void* d_ws, size_t ws_size,
                              hipStream_t stream) {
    const float*        Q = (const float*)d_in[0];
    const float*        K = (const float*)d_in[1];
    const float*        V = (const float*)d_in[2];
    const unsigned int* M = (const unsigned int*)d_in[3];

    float* out  = (float*)d_out;
    float* outO = out;                                    // [B,H,S,D]
    float* outP = out + (size_t)NB * NH * SQ * DH;        // [B,H,S,S]

    // workspace: mask bits (2 MB) | K tiled bf16 (16.8 MB) | V tiled (16.8 MB)
    unsigned int* mbits = (unsigned int*)d_ws;
    short* Ktg = (short*)(mbits + (size_t)NB * SQ * 64);
    short* Vtg = Ktg + (size_t)NB * NH * SQ * DH;

    hipLaunchKernelGGL(mask_pack, dim3(NB * SQ), dim3(64), 0, stream, M, mbits);
    hipLaunchKernelGGL(kv_pack, dim3(NB * NH * 32), dim3(256), 0, stream, K, V, Ktg, Vtg);
    hipLaunchKernelGGL(attn_fused, dim3(SQ / QB, NB * NH), dim3(256), 0, stream,
                       Q, Ktg, Vtg, mbits, outO, outP);
}

// Round 5
// 529.988 us; speedup vs baseline: 1.0331x; 1.0331x over previous
//
#include <hip/hip_runtime.h>
#include <math.h>

#define SQ   2048
#define DH   64
#define NH   16
#define NB   4
#define QB   128     // q rows per block (8 waves x 16)
#define WVS  8
#define TK   64      // k rows per tile
#define PPD  72      // Ps row stride in shorts (144B: 16B-aligned, 4-bank rotate/row)

typedef float f32x4  __attribute__((ext_vector_type(4)));
typedef short s16x8  __attribute__((ext_vector_type(8)));
typedef short s16x4  __attribute__((ext_vector_type(4)));

__device__ __forceinline__ short f2bf(float f) {
    union { float f; unsigned u; } x; x.f = f;
    unsigned r = (x.u + 0x7FFFu + ((x.u >> 16) & 1u)) >> 16;  // RNE
    return (short)(unsigned short)r;
}

__device__ __forceinline__ void gll16(const void* g, void* l) {
    __builtin_amdgcn_global_load_lds(
        (const __attribute__((address_space(1))) unsigned int*)g,
        (__attribute__((address_space(3))) unsigned int*)l, 16, 0, 0);
}

// -------- prepack 1: mask -> transposed bitmask  mb[b][word][row] ----------
__global__ __launch_bounds__(64)
void mask_pack(const unsigned int* __restrict__ Mg, unsigned int* __restrict__ mb)
{
    const int gr   = blockIdx.x;           // 0 .. NB*SQ-1
    const int b    = gr >> 11;
    const int s    = gr & (SQ - 1);
    const int lane = threadIdx.x;
    bool byteLayout = false;
    #pragma unroll
    for (int i = 0; i < 16; ++i) byteLayout = byteLayout || (Mg[i] > 1u);
    unsigned int* out = mb + (size_t)b * 64 * SQ + s;
    if (!byteLayout) {
        const unsigned int* rp = Mg + (size_t)gr * SQ;
        #pragma unroll 4
        for (int i = 0; i < 32; ++i) {
            unsigned long long bits = __ballot(rp[i * 64 + lane] != 0u);
            if (lane == 0) {
                out[(size_t)(2*i)   * SQ] = (unsigned)bits;
                out[(size_t)(2*i+1) * SQ] = (unsigned)(bits >> 32);
            }
        }
    } else {
        const unsigned char* rp = (const unsigned char*)Mg + (size_t)gr * SQ;
        #pragma unroll 4
        for (int i = 0; i < 32; ++i) {
            unsigned long long bits = __ballot(rp[i * 64 + lane] != 0);
            if (lane == 0) {
                out[(size_t)(2*i)   * SQ] = (unsigned)bits;
                out[(size_t)(2*i+1) * SQ] = (unsigned)(bits >> 32);
            }
        }
    }
}

// ------- prepack 2: K,V f32 -> bf16, tiled 64x64, XOR-swizzled granules ------
__global__ __launch_bounds__(256)
void kv_pack(const float* __restrict__ Kg, const float* __restrict__ Vg,
             short* __restrict__ Ktg, short* __restrict__ Vtg)
{
    __shared__ float Vf[64][68];
    const int tid = threadIdx.x;
    const int bh  = blockIdx.x >> 5;
    const int kt  = blockIdx.x & 31;
    const float* ksrc = Kg + ((size_t)bh * SQ + kt * TK) * DH;
    const float* vsrc = Vg + ((size_t)bh * SQ + kt * TK) * DH;
    short* kd = Ktg + (size_t)(bh * 32 + kt) * 4096;
    short* vd = Vtg + (size_t)(bh * 32 + kt) * 4096;

    #pragma unroll
    for (int ii = 0; ii < 4; ++ii) {
        int idx = tid + ii * 256;          // 0..1023 float4 slots
        int r = idx >> 4, c0 = (idx & 15) * 4;
        float4 kv = *(const float4*)(ksrc + r * DH + c0);
        s16x4 s; s[0]=f2bf(kv.x); s[1]=f2bf(kv.y); s[2]=f2bf(kv.z); s[3]=f2bf(kv.w);
        int gp = (c0 >> 3) ^ (r & 7);
        *(s16x4*)(kd + r * 64 + gp * 8 + (c0 & 7)) = s;
        float4 vv = *(const float4*)(vsrc + r * DH + c0);
        *(float4*)&Vf[r][c0] = vv;
    }
    __syncthreads();
    #pragma unroll
    for (int ii = 0; ii < 4; ++ii) {
        int idx = tid + ii * 256;
        int d = idx >> 4, k0 = (idx & 15) * 4;
        s16x4 s;
        s[0]=f2bf(Vf[k0+0][d]); s[1]=f2bf(Vf[k0+1][d]);
        s[2]=f2bf(Vf[k0+2][d]); s[3]=f2bf(Vf[k0+3][d]);
        int gp = (k0 >> 3) ^ (d & 7);
        *(s16x4*)(vd + d * 64 + gp * 8 + (k0 & 7)) = s;
    }
}

// ------------------------------- hot kernel ---------------------------------
// 8 waves x 16 q-rows. LDS = 16K (Ks dbuf) + 16K (Vt dbuf) + 18K (Ps bf16)
// = 51.2 KB -> 3 blocks/CU = 24 waves/CU.
__global__ __launch_bounds__(512)
void attn_fused(const float* __restrict__ Qg,
                const short* __restrict__ Ktg, const short* __restrict__ Vtg,
                const unsigned int* __restrict__ mb,
                float* __restrict__ Og, float* __restrict__ Pg)
{
    __shared__ __align__(16) short Ks[2][4096];      // dbuf swizzled K tile
    __shared__ __align__(16) short Vt[2][4096];      // dbuf swizzled V^T tile
    __shared__ __align__(16) short Psh[WVS][16][PPD];// per-wave P tile (bf16)

    const int tid  = threadIdx.x;
    const int lane = tid & 63;
    const int wv   = tid >> 6;        // 0..7
    const int lq   = lane & 15;
    const int lk   = lane >> 4;

    const int bh = blockIdx.y;
    const int b  = bh >> 4;
    const int q0 = blockIdx.x * QB;

    // ---- Q A-fragments, pre-scaled by 1/sqrt(d)=0.125 (exact in bf16) ----
    s16x8 qf[2];
    {
        const float* qrow = Qg + ((size_t)bh * SQ + q0 + wv * 16 + lq) * DH;
        #pragma unroll
        for (int c = 0; c < 2; ++c) {
            const float4* p = (const float4*)(qrow + c * 32 + lk * 8);
            float4 a = p[0], bb = p[1];
            qf[c][0]=f2bf(0.125f*a.x);  qf[c][1]=f2bf(0.125f*a.y);
            qf[c][2]=f2bf(0.125f*a.z);  qf[c][3]=f2bf(0.125f*a.w);
            qf[c][4]=f2bf(0.125f*bb.x); qf[c][5]=f2bf(0.125f*bb.y);
            qf[c][6]=f2bf(0.125f*bb.z); qf[c][7]=f2bf(0.125f*bb.w);
        }
    }

    const size_t ktb  = (size_t)bh * 32;
    const int    stgo = wv * 512 + lane * 8;   // one gll16/wave covers the 4096-short tile
    const int swz0 = (lk ^ (lq & 7)) << 3;
    const int swz1 = ((4 + lk) ^ (lq & 7)) << 3;
    const size_t mbase = (size_t)b * 64 * SQ + q0 + wv * 16
                       + ((size_t)((lane >> 4) & 1)) * SQ + (lane & 15);

    // ================= sweep 1: row max m, denom l =================
    float m[4], l[4];
    #pragma unroll
    for (int r = 0; r < 4; ++r) { m[r] = -3.3e38f; l[r] = 0.f; }

    gll16(Ktg + ktb * 4096 + stgo, &Ks[0][stgo]);   // prologue tile 0
    __syncthreads();

    #pragma unroll 1
    for (int kt = 0; kt < SQ / TK; ++kt) {
        const int cb = kt & 1;
        if (kt + 1 < SQ / TK)
            gll16(Ktg + (ktb + kt + 1) * 4096 + stgo, &Ks[cb ^ 1][stgo]);
        const unsigned mw = mb[mbase + (size_t)(kt * 2) * SQ];

        f32x4 acc[4];
        #pragma unroll
        for (int nt = 0; nt < 4; ++nt) {
            acc[nt] = (f32x4){0.f, 0.f, 0.f, 0.f};
            const int R = nt * 16 + lq;
            s16x8 kf0 = *(const s16x8*)(&Ks[cb][R * 64] + swz0);
            s16x8 kf1 = *(const s16x8*)(&Ks[cb][R * 64] + swz1);
            acc[nt] = __builtin_amdgcn_mfma_f32_16x16x32_bf16(qf[0], kf0, acc[nt], 0, 0, 0);
            acc[nt] = __builtin_amdgcn_mfma_f32_16x16x32_bf16(qf[1], kf1, acc[nt], 0, 0, 0);
        }
        #pragma unroll
        for (int r = 0; r < 4; ++r) {
            const unsigned bits0 = __shfl(mw, lk * 4 + r, 64);
            const unsigned bits1 = __shfl(mw, 16 + lk * 4 + r, 64);
            float w[4];
            #pragma unroll
            for (int nt = 0; nt < 4; ++nt) {
                float x = acc[nt][r];
                unsigned bits = (nt < 2) ? bits0 : bits1;
                if ((bits >> ((nt * 16 + lq) & 31)) & 1u) x = -1e30f;
                w[nt] = x;
            }
            float tmax = fmaxf(fmaxf(w[0], w[1]), fmaxf(w[2], w[3]));
            float lt = __expf(w[0]-tmax) + __expf(w[1]-tmax) + __expf(w[2]-tmax) + __expf(w[3]-tmax);
            float mn = fmaxf(m[r], tmax);
            l[r] = l[r] * __expf(m[r] - mn) + lt * __expf(tmax - mn);
            m[r] = mn;
        }
        __syncthreads();
    }

    // ---- reduce (m,l) across the 16 column-lanes of each row group ----
    float linv[4];
    #pragma unroll
    for (int r = 0; r < 4; ++r) {
        #pragma unroll
        for (int x = 1; x < 16; x <<= 1) {
            float mo = __shfl_xor(m[r], x, 64);
            float lo = __shfl_xor(l[r], x, 64);
            float mn = fmaxf(m[r], mo);
            l[r] = l[r] * __expf(m[r] - mn) + lo * __expf(mo - mn);
            m[r] = mn;
        }
        linv[r] = 1.0f / l[r];
    }

    // ================= sweep 2: P write + O = P.V =================
    f32x4 oa[4];
    #pragma unroll
    for (int dt = 0; dt < 4; ++dt) oa[dt] = (f32x4){0.f, 0.f, 0.f, 0.f};

    {   // prologue: stage K+V tile 0
        gll16(Ktg + ktb * 4096 + stgo, &Ks[0][stgo]);
        gll16(Vtg + ktb * 4096 + stgo, &Vt[0][stgo]);
    }
    __syncthreads();

    float* Pdir = Pg + (size_t)bh * SQ * SQ + (size_t)(q0 + wv * 16) * SQ;

    #pragma unroll 1
    for (int kt = 0; kt < SQ / TK; ++kt) {
        const int cb = kt & 1;
        if (kt + 1 < SQ / TK) {
            gll16(Ktg + (ktb + kt + 1) * 4096 + stgo, &Ks[cb ^ 1][stgo]);
            gll16(Vtg + (ktb + kt + 1) * 4096 + stgo, &Vt[cb ^ 1][stgo]);
        }
        const unsigned mw = mb[mbase + (size_t)(kt * 2) * SQ];
        unsigned b0[4], b1[4];
        #pragma unroll
        for (int r = 0; r < 4; ++r) {
            b0[r] = __shfl(mw, lk * 4 + r, 64);
            b1[r] = __shfl(mw, 16 + lk * 4 + r, 64);
        }

        #pragma unroll
        for (int nt = 0; nt < 4; ++nt) {
            f32x4 acc = {0.f, 0.f, 0.f, 0.f};
            const int R = nt * 16 + lq;
            s16x8 kf0 = *(const s16x8*)(&Ks[cb][R * 64] + swz0);
            s16x8 kf1 = *(const s16x8*)(&Ks[cb][R * 64] + swz1);
            acc = __builtin_amdgcn_mfma_f32_16x16x32_bf16(qf[0], kf0, acc, 0, 0, 0);
            acc = __builtin_amdgcn_mfma_f32_16x16x32_bf16(qf[1], kf1, acc, 0, 0, 0);
            #pragma unroll
            for (int r = 0; r < 4; ++r) {
                float x = acc[r];
                unsigned bits = (nt < 2) ? b0[r] : b1[r];
                if ((bits >> ((nt * 16 + lq) & 31)) & 1u) x = -1e30f;
                float p = __expf(x - m[r]) * linv[r];
                // f32 P straight from the register (proven not to inflate WRITE_SIZE)
                Pdir[(size_t)(lk * 4 + r) * SQ + kt * TK + nt * 16 + lq] = p;
                Psh[wv][lk * 4 + r][nt * 16 + lq] = f2bf(p);
            }
        }
        // Psh is per-wave: wave-local LDS drain + scheduling fence (rule #18)
        asm volatile("s_waitcnt lgkmcnt(0)" ::: "memory");
        __builtin_amdgcn_sched_barrier(0);

        // PV MFMAs: A = bf16 P fragments read directly from Psh
        #pragma unroll
        for (int c = 0; c < 2; ++c) {
            s16x8 pa = *(const s16x8*)&Psh[wv][lq][c * 32 + lk * 8];
            #pragma unroll
            for (int dt = 0; dt < 4; ++dt) {
                const int Rv = dt * 16 + lq;
                const int swzv = (((4 * c + lk) ^ (lq & 7)) << 3);
                s16x8 vb = *(const s16x8*)(&Vt[cb][Rv * 64] + swzv);
                oa[dt] = __builtin_amdgcn_mfma_f32_16x16x32_bf16(pa, vb, oa[dt], 0, 0, 0);
            }
        }
        __syncthreads();   // prefetch drain + Ks/Vt WAR
    }

    // ---- write O ----
    {
        float* orow = Og + ((size_t)bh * SQ + q0 + wv * 16) * DH;
        #pragma unroll
        for (int dt = 0; dt < 4; ++dt)
            #pragma unroll
            for (int r = 0; r < 4; ++r)
                orow[(size_t)(lk * 4 + r) * DH + dt * 16 + lq] = oa[dt][r];
    }
}

extern "C" void kernel_launch(void* const* d_in, const int* in_sizes, int n_in,
                              void* d_out, int out_size, void* d_ws, size_t ws_size,
                              hipStream_t stream) {
    const float*        Q = (const float*)d_in[0];
    const float*        K = (const float*)d_in[1];
    const float*        V = (const float*)d_in[2];
    const unsigned int* M = (const unsigned int*)d_in[3];

    float* out  = (float*)d_out;
    float* outO = out;                                    // [B,H,S,D]
    float* outP = out + (size_t)NB * NH * SQ * DH;        // [B,H,S,S]

    // workspace: mask bits (2 MB) | K tiled bf16 (16.8 MB) | V tiled (16.8 MB)
    unsigned int* mbits = (unsigned int*)d_ws;
    short* Ktg = (short*)(mbits + (size_t)NB * SQ * 64);
    short* Vtg = Ktg + (size_t)NB * NH * SQ * DH;

    hipLaunchKernelGGL(mask_pack, dim3(NB * SQ), dim3(64), 0, stream, M, mbits);
    hipLaunchKernelGGL(kv_pack, dim3(NB * NH * 32), dim3(256), 0, stream, K, V, Ktg, Vtg);
    hipLaunchKernelGGL(attn_fused, dim3(SQ / QB, NB * NH), dim3(512), 0, stream,
                       Q, Ktg, Vtg, mbits, outO, outP);
}